// Round 6
// baseline (297.448 us; speedup 1.0000x reference)
//
#include <hip/hip_runtime.h>
#include <hip/hip_bf16.h>
#include <stdint.h>

typedef unsigned short ushort_t;
typedef unsigned long long u64;
typedef __attribute__((ext_vector_type(8))) short short8;   // 8 bf16 (4 VGPRs)
typedef __attribute__((ext_vector_type(4))) float f32x4;

#define N_NODES 384
#define HF      512
#define IT      12        // i-rows per attention unit: 32 tiles x 8 heads = 256
#define NBLK    256

__device__ inline ushort_t f2bf(float f) {
  __hip_bfloat16 b = __float2bfloat16(f);
  return *reinterpret_cast<ushort_t*>(&b);
}
__device__ inline float bf2f_u(ushort_t u) {
  union { float f; uint32_t i; } v; v.i = ((uint32_t)u) << 16; return v.f;
}

// Zero the spin-barrier counters (ws is re-poisoned 0xAA before every call).
__global__ void init_bar(unsigned* bar) {
  if (threadIdx.x < 8) bar[threadIdx.x] = 0;
}

// Device-scope grid barrier. 256 blocks x 6 waves, 56 KB LDS -> 2 blocks/CU
// capacity, so all NBLK blocks are co-resident; counting barrier is safe.
// __threadfence() release (all threads, pre-arrive) + acquire (post-spin).
__device__ __forceinline__ void gridbar(unsigned* cnt) {
  __threadfence();                 // flush this thread's writes device-scope
  __syncthreads();
  if (threadIdx.x == 0) {
    if (atomicAdd(cnt, 1u) + 1u < NBLK) {
      while (__hip_atomic_load(cnt, __ATOMIC_RELAXED,
                               __HIP_MEMORY_SCOPE_AGENT) < NBLK) {
        __builtin_amdgcn_s_sleep(2);
      }
    }
    __threadfence();               // invalidate CU caches before reads
  }
  __syncthreads();
}

// ---------------------------------------------------------------------------
// GEMM phase: waves 0..2 of each block each compute one 16m x 32n tile.
// unit u = blockIdx.x*3 + wave in [0,768): m0=(u>>5)*16, n0=(u&31)*32.
//  n <  512 (gl): glb bf16 [m][n]
//  n >= 512 (gr): G fp32 [m][512+n'] and grT bf16 [n'][m] (k-contig)
// ---------------------------------------------------------------------------
__device__ __forceinline__ void gemm_phase(
    const ushort_t* A, const ushort_t* WT,
    float* G, ushort_t* glb, ushort_t* grT)
{
  const int t = threadIdx.x, wave = t >> 6, lane = t & 63;
  if (wave < 3) {
    const int u = blockIdx.x * 3 + wave;
    const int m0 = (u >> 5) * 16;
    const int n0 = (u & 31) * 32;
    const int lm = lane & 15, q = lane >> 4;

    const short8* Ap = (const short8*)A;    // [m][64] short8 chunks
    const short8* Bp = (const short8*)WT;   // [n][64] short8 chunks
    const int arow  = (m0 + lm) * 64 + q;
    const int brow0 = (n0 + lm) * 64 + q;
    const int brow1 = (n0 + 16 + lm) * 64 + q;

    f32x4 acc0 = {0.f, 0.f, 0.f, 0.f};
    f32x4 acc1 = {0.f, 0.f, 0.f, 0.f};
#pragma unroll
    for (int kc = 0; kc < 16; ++kc) {
      short8 af = Ap[arow  + kc * 4];
      short8 b0 = Bp[brow0 + kc * 4];
      short8 b1 = Bp[brow1 + kc * 4];
      acc0 = __builtin_amdgcn_mfma_f32_16x16x32_bf16(af, b0, acc0, 0, 0, 0);
      acc1 = __builtin_amdgcn_mfma_f32_16x16x32_bf16(af, b1, acc1, 0, 0, 0);
    }
    if (n0 < 512) {
#pragma unroll
      for (int r = 0; r < 4; ++r) {
        int m = m0 + q * 4 + r;
        glb[m * HF + n0 + lm]      = f2bf(acc0[r]);
        glb[m * HF + n0 + 16 + lm] = f2bf(acc1[r]);
      }
    } else {
#pragma unroll
      for (int r = 0; r < 4; ++r) {
        int m = m0 + q * 4 + r;
        G[m * 1024 + n0 + lm]      = acc0[r];
        G[m * 1024 + n0 + 16 + lm] = acc1[r];
      }
      int c0 = n0 - 512;
      uint2 p0, p1;
      p0.x = (uint32_t)f2bf(acc0[0]) | ((uint32_t)f2bf(acc0[1]) << 16);
      p0.y = (uint32_t)f2bf(acc0[2]) | ((uint32_t)f2bf(acc0[3]) << 16);
      p1.x = (uint32_t)f2bf(acc1[0]) | ((uint32_t)f2bf(acc1[1]) << 16);
      p1.y = (uint32_t)f2bf(acc1[2]) | ((uint32_t)f2bf(acc1[3]) << 16);
      *(uint2*)&grT[(c0 + lm) * 384 + m0 + q * 4]      = p0;
      *(uint2*)&grT[(c0 + 16 + lm) * 384 + m0 + q * 4] = p1;
    }
  }
}

// ---------------------------------------------------------------------------
// Attention phase: block = (12-row i-tile, head) = blockIdx (256 units).
// leaky(z)=0.6z+0.4|z| => e = 0.6(bl_j+br_i)+0.4*sum a_f|z|. Thread t = j.
// layer 0: ELU + x residual -> xcur fp32, x1b bf16. layer 1: +xcur -> fout.
// ---------------------------------------------------------------------------
__device__ __forceinline__ void attn_phase(int layer,
    const float* G, const ushort_t* glb, const ushort_t* grT,
    const u64* mbits, const float* resid, const float* avec,
    float* xcur, ushort_t* x1b, float* fout,
    char* smem, float* s_bri, u64 (*s_mask)[6])
{
  ushort_t (*s_gl)[72]     = (ushort_t(*)[72])smem;          // 55296 B
  float    (*s_e)[N_NODES] = (float(*)[N_NODES])smem;        // 12x384 fp32
  ushort_t (*s_pb)[392]    = (ushort_t(*)[392])(smem + 18432); // 16x392 bf16

  const int t = threadIdx.x, lane = t & 63, wave = t >> 6;
  const int i0 = (blockIdx.x >> 3) * IT, h = blockIdx.x & 7;

  // masks (72 u64) on t<72; bri dot on t in [128,320)
  if (t < 72) ((u64*)s_mask)[t] = mbits[i0 * 6 + t];
  if (t >= 128 && t < 320) {
    int u = t - 128, il = u >> 4, fg = u & 15;
    float4 g4 = *(const float4*)(G + (i0 + il) * 1024 + 512 + h * 64 + fg * 4);
    float4 a4 = *(const float4*)(avec + fg * 4);
    float s = a4.x * g4.x + a4.y * g4.y + a4.z * g4.z + a4.w * g4.w;
    s += __shfl_xor(s, 1); s += __shfl_xor(s, 2);
    s += __shfl_xor(s, 4); s += __shfl_xor(s, 8);
    if (fg == 0) s_bri[il] = s;
  }
  // stage all 384 gl rows (bf16) coalesced into LDS
#pragma unroll
  for (int rep = 0; rep < 8; ++rep) {
    int idx = rep * 384 + t, row = idx >> 3, c = idx & 7;
    *(short8*)&s_gl[row][c * 8] =
        *(const short8*)&glb[row * HF + h * 64 + c * 8];
  }
  __syncthreads();

  float gl[64], av[64];
  {
    const short8* rowp = (const short8*)&s_gl[t][0];
#pragma unroll
    for (int c = 0; c < 8; ++c) {
      short8 v = rowp[c];
#pragma unroll
      for (int u2 = 0; u2 < 8; ++u2)
        gl[c * 8 + u2] = bf2f_u((ushort_t)v[u2]);
    }
#pragma unroll
    for (int c = 0; c < 16; ++c) {
      float4 a4 = ((const float4*)avec)[c];
      av[c * 4] = a4.x; av[c * 4 + 1] = a4.y;
      av[c * 4 + 2] = a4.z; av[c * 4 + 3] = a4.w;
    }
  }
  float accl = 0.f;
#pragma unroll
  for (int f = 0; f < 64; ++f) accl += av[f] * gl[f];
  __syncthreads();   // s_gl dead; region becomes s_e / s_pb

  const int jw = t >> 6, jb = t & 63;
#pragma unroll
  for (int il = 0; il < IT; ++il) {
    const float4* gr4 = (const float4*)(G + (i0 + il) * 1024 + 512 + h * 64);
    float acc = 0.f;
#pragma unroll
    for (int c = 0; c < 16; ++c) {
      float4 g4 = gr4[c];
      acc += av[c * 4]     * fabsf(gl[c * 4]     + g4.x);
      acc += av[c * 4 + 1] * fabsf(gl[c * 4 + 1] + g4.y);
      acc += av[c * 4 + 2] * fabsf(gl[c * 4 + 2] + g4.z);
      acc += av[c * 4 + 3] * fabsf(gl[c * 4 + 3] + g4.w);
    }
    bool m = (s_mask[il][jw] >> jb) & 1;
    float e = 0.6f * (accl + s_bri[il]) + 0.4f * acc;
    s_e[il][t] = m ? e : -1e30f;
  }
#pragma unroll
  for (int r4 = 0; r4 < 4; ++r4) s_pb[IT + r4][t] = 0;  // zero P rows 12..15
  __syncthreads();

  // softmax over j per row; write normalized P bf16
  for (int il = wave; il < IT; il += 6) {
    float v[6];
    float mx = -1e30f;
#pragma unroll
    for (int c = 0; c < 6; ++c) { v[c] = s_e[il][lane + 64 * c]; mx = fmaxf(mx, v[c]); }
#pragma unroll
    for (int off = 32; off; off >>= 1) mx = fmaxf(mx, __shfl_xor(mx, off));
    float sum = 0.f;
#pragma unroll
    for (int c = 0; c < 6; ++c) { v[c] = __expf(v[c] - mx); sum += v[c]; }
#pragma unroll
    for (int off = 32; off; off >>= 1) sum += __shfl_xor(sum, off);
    float inv = 1.0f / sum;
#pragma unroll
    for (int c = 0; c < 6; ++c) s_pb[il][lane + 64 * c] = f2bf(v[c] * inv);
  }
  __syncthreads();

  // MFMA aggregation out[12 i][64 f] = P[12][384] @ gr[384][64]
  if (wave < 4) {
    const int lm = lane & 15, q = lane >> 4;
    const int f0 = wave * 16;
    const ushort_t* Brow = grT + (h * 64 + f0 + lm) * 384;
    f32x4 acc = {0.f, 0.f, 0.f, 0.f};
#pragma unroll
    for (int kc = 0; kc < 12; ++kc) {
      short8 af = *(const short8*)&s_pb[lm][kc * 32 + q * 8];
      short8 bf = *(const short8*)&Brow[kc * 32 + q * 8];
      acc = __builtin_amdgcn_mfma_f32_16x16x32_bf16(af, bf, acc, 0, 0, 0);
    }
    if (q < 3) {                                    // D rows 0..11
#pragma unroll
      for (int r = 0; r < 4; ++r) {
        int i = i0 + q * 4 + r;
        int off = i * HF + h * 64 + f0 + lm;
        float o = acc[r];
        if (layer == 0) {
          float oe = (o > 0.f) ? o : (__expf(o) - 1.f);   // ELU
          float vv = resid[off] + oe;
          xcur[off] = vv;
          x1b[off]  = f2bf(vv);
        } else {
          fout[off] = resid[off] + o;
        }
      }
    }
  }
}

// ---------------------------------------------------------------------------
// Mega kernel: prep | gemm0 | attn0 | gemm1 | attn1, grid-synced in-kernel.
// grid 256 x 384 threads (6 waves, ~56 KB LDS -> co-residency guaranteed).
// ---------------------------------------------------------------------------
__global__ __launch_bounds__(384) void mega(
    const float* __restrict__ x, const int* __restrict__ adj,
    const float* __restrict__ Wl0, const float* __restrict__ Wr0,
    const float* __restrict__ a0,  const float* __restrict__ Wl1,
    const float* __restrict__ Wr1, const float* __restrict__ a1,
    float* out, ushort_t* WT0, ushort_t* WT1, ushort_t* xb,
    float* G, ushort_t* glb, ushort_t* grT, ushort_t* x1b,
    u64* mbits, float* xcur, unsigned* bar)
{
  __shared__ __align__(16) char smem[55296];
  __shared__ float s_bri[IT];
  __shared__ u64   s_mask[IT][6];

  const int t = threadIdx.x, b = blockIdx.x;
  const int lane = t & 63, wave = t >> 6;

  // ---------- phase P: prep (transposes, x cast, adjacency bitmasks) ----------
  {
    ushort_t (*tile)[33] = (ushort_t(*)[33])smem;
    for (int rep = 0; rep < 4; ++rep) {
      int tau = b * 4 + rep;                 // 0..1023
      int z = tau >> 8, tid = tau & 255;
      const float* W = (z == 0) ? Wl0 : (z == 1) ? Wr0 : (z == 2) ? Wl1 : Wr1;
      ushort_t* WT = ((z < 2) ? WT0 : WT1) + (z & 1) * (512 * 512);
      int n0 = (tid & 15) * 32, k0 = (tid >> 4) * 32;
      if (t < 256) {
#pragma unroll
        for (int qq = 0; qq < 4; ++qq) {
          int idx = t + qq * 256, r = idx >> 5, c = idx & 31;
          tile[r][c] = f2bf(W[(k0 + r) * 512 + n0 + c]);
        }
      }
      __syncthreads();
      if (t < 256) {
#pragma unroll
        for (int qq = 0; qq < 4; ++qq) {
          int idx = t + qq * 256, r = idx >> 5, c = idx & 31;
          WT[(n0 + r) * 512 + k0 + c] = tile[c][r];
        }
      }
      __syncthreads();
    }
  }
#pragma unroll
  for (int r = 0; r < 2; ++r) {              // x -> bf16 (768 elems/block)
    int i = b * 768 + r * 384 + t;
    xb[i] = f2bf(x[i]);
  }
  {                                          // adjacency bitmasks
    int row = b;
    int j = wave * 64 + lane;
    u64 m = __ballot(adj[row * N_NODES + j] != 0 || row == j);
    if (lane == 0) mbits[row * 6 + wave] = m;
    if (b < 128) {
      row = 256 + b;
      m = __ballot(adj[row * N_NODES + j] != 0 || row == j);
      if (lane == 0) mbits[row * 6 + wave] = m;
    }
  }
  gridbar(bar + 0);

  gemm_phase(xb, WT0, G, glb, grT);
  gridbar(bar + 1);

  attn_phase(0, G, glb, grT, mbits, x, a0, xcur, x1b, out,
             smem, s_bri, s_mask);
  gridbar(bar + 2);

  gemm_phase(x1b, WT1, G, glb, grT);
  gridbar(bar + 3);

  attn_phase(1, G, glb, grT, mbits, xcur, a1, xcur, x1b, out,
             smem, s_bri, s_mask);
}

// ---------------------------------------------------------------------------
extern "C" void kernel_launch(void* const* d_in, const int* in_sizes, int n_in,
                              void* d_out, int out_size, void* d_ws, size_t ws_size,
                              hipStream_t stream) {
  const float* x   = (const float*)d_in[0];
  const int*   adj = (const int*)d_in[1];
  const float* Wl0 = (const float*)d_in[2];
  const float* Wr0 = (const float*)d_in[3];
  const float* a0  = (const float*)d_in[4];
  const float* Wl1 = (const float*)d_in[5];
  const float* Wr1 = (const float*)d_in[6];
  const float* a1  = (const float*)d_in[7];
  float* out = (float*)d_out;

  char* ws = (char*)d_ws;
  ushort_t* WT0  = (ushort_t*)(ws + 0L);            // 1 MB  [Wl0;Wr0]^T bf16
  ushort_t* WT1  = (ushort_t*)(ws + (1L << 20));    // 1 MB
  ushort_t* xb   = (ushort_t*)(ws + (2L << 20));    // 384 KB x bf16
  float*    G    = (float*)   (ws + (3L << 20));    // 1.5 MB (gr half used)
  ushort_t* grT  = (ushort_t*)(ws + (5L << 20));    // 384 KB gr^T bf16
  ushort_t* x1b  = (ushort_t*)(ws + (6L << 20));    // 384 KB
  ushort_t* glb  = (ushort_t*)(ws + (7L << 20));    // 384 KB gl bf16
  u64*      mbits= (u64*)     (ws + (8L << 20));    // 18 KB adjacency bits
  float*    xcur = (float*)   (ws + (9L << 20));    // 768 KB fp32 residual
  unsigned* bar  = (unsigned*)(ws + (10L << 20));   // 8 barrier counters

  init_bar<<<1, 64, 0, stream>>>(bar);
  mega<<<NBLK, 384, 0, stream>>>(x, adj, Wl0, Wr0, a0, Wl1, Wr1, a1, out,
                                 WT0, WT1, xb, G, glb, grT, x1b, mbits,
                                 xcur, bar);
}

// Round 7
// 124.097 us; speedup vs baseline: 2.3969x; 2.3969x over previous
//
#include <hip/hip_runtime.h>
#include <hip/hip_bf16.h>
#include <stdint.h>

typedef unsigned short ushort_t;
typedef unsigned long long u64;
typedef __attribute__((ext_vector_type(8))) short short8;   // 8 bf16 (4 VGPRs)
typedef __attribute__((ext_vector_type(4))) float f32x4;

#define N_NODES 384
#define HF      512
#define IT      12        // i-rows per attention block: 32 tiles x 8 heads = 256

__device__ inline ushort_t f2bf(float f) {
  __hip_bfloat16 b = __float2bfloat16(f);
  return *reinterpret_cast<ushort_t*>(&b);
}
__device__ inline float bf2f_u(ushort_t u) {
  union { float f; uint32_t i; } v; v.i = ((uint32_t)u) << 16; return v.f;
}
__device__ inline short8 pack8(const float* s) {
  short8 r;
#pragma unroll
  for (int j = 0; j < 8; ++j) r[j] = (short)f2bf(s[j]);
  return r;
}

// ---------------------------------------------------------------------------
// Kernel 1/3: dual GEMM, raw fp32 inputs (no pre-transpose, no prep kernel).
// G[m][n] = sum_k X[m][k] * W[k][n], n in [0,1024), W = [WL | WR] fp32.
// In-register fp32->bf16 cvt for both operands (same RNE numerics as before).
//  n <  512 (gl): glb bf16 [m][n]
//  n >= 512 (gr): G fp32 [m][512+n'] and grT bf16 [n'][m] (k-contig)
// Layer 0 extra: adjacency bitmasks (blocks with by==0).
// grid (24, 8), 256 threads = 4 waves; wave computes 16m x 32n.
// ---------------------------------------------------------------------------
__global__ __launch_bounds__(256) void gemm_direct(
    const float* __restrict__ X, const float* __restrict__ WL,
    const float* __restrict__ WR, float* __restrict__ G,
    ushort_t* __restrict__ glb, ushort_t* __restrict__ grT,
    const int* __restrict__ adj, u64* __restrict__ mbits)
{
  const int t = threadIdx.x, wave = t >> 6, lane = t & 63;
  const int lm = lane & 15, q = lane >> 4;
  const int m0 = blockIdx.x * 16;
  const int n0 = (blockIdx.y * 4 + wave) * 32;
  const float* Wp = (n0 < 512) ? (WL + n0) : (WR + (n0 - 512));
  const float* Arow = X + (m0 + lm) * HF;

  f32x4 acc0 = {0.f, 0.f, 0.f, 0.f};
  f32x4 acc1 = {0.f, 0.f, 0.f, 0.f};
#pragma unroll 4
  for (int kc = 0; kc < 16; ++kc) {
    const int kbase = kc * 32 + q * 8;
    float4 a0 = *(const float4*)(Arow + kbase);
    float4 a1 = *(const float4*)(Arow + kbase + 4);
    float av8[8] = {a0.x, a0.y, a0.z, a0.w, a1.x, a1.y, a1.z, a1.w};
    short8 af = pack8(av8);
    float b0f[8], b1f[8];
#pragma unroll
    for (int j = 0; j < 8; ++j) {
      const float* r = Wp + (kbase + j) * HF;   // 64 lanes -> ~4 lines/instr
      b0f[j] = r[lm];
      b1f[j] = r[16 + lm];
    }
    short8 b0 = pack8(b0f);
    short8 b1 = pack8(b1f);
    acc0 = __builtin_amdgcn_mfma_f32_16x16x32_bf16(af, b0, acc0, 0, 0, 0);
    acc1 = __builtin_amdgcn_mfma_f32_16x16x32_bf16(af, b1, acc1, 0, 0, 0);
  }
  if (n0 < 512) {
#pragma unroll
    for (int r = 0; r < 4; ++r) {
      int m = m0 + q * 4 + r;
      glb[m * HF + n0 + lm]      = f2bf(acc0[r]);
      glb[m * HF + n0 + 16 + lm] = f2bf(acc1[r]);
    }
  } else {
#pragma unroll
    for (int r = 0; r < 4; ++r) {
      int m = m0 + q * 4 + r;
      G[m * 1024 + n0 + lm]      = acc0[r];
      G[m * 1024 + n0 + 16 + lm] = acc1[r];
    }
    int c0 = n0 - 512;
    uint2 p0, p1;
    p0.x = (uint32_t)f2bf(acc0[0]) | ((uint32_t)f2bf(acc0[1]) << 16);
    p0.y = (uint32_t)f2bf(acc0[2]) | ((uint32_t)f2bf(acc0[3]) << 16);
    p1.x = (uint32_t)f2bf(acc1[0]) | ((uint32_t)f2bf(acc1[1]) << 16);
    p1.y = (uint32_t)f2bf(acc1[2]) | ((uint32_t)f2bf(acc1[3]) << 16);
    *(uint2*)&grT[(c0 + lm) * 384 + m0 + q * 4]      = p0;
    *(uint2*)&grT[(c0 + 16 + lm) * 384 + m0 + q * 4] = p1;
  }
  // layer-0 only: adjacency bitmasks (self-loop OR'd in), by==0 blocks
  if (adj != nullptr && blockIdx.y == 0) {
    int rbase = (blockIdx.x * 4 + wave) * 4;
    for (int rr = 0; rr < 4; ++rr) {
      int row = rbase + rr;
#pragma unroll
      for (int w = 0; w < 6; ++w) {
        int j = w * 64 + lane;
        u64 m = __ballot(adj[row * N_NODES + j] != 0 || row == j);
        if (lane == 0) mbits[row * 6 + w] = m;
      }
    }
  }
}

// ---------------------------------------------------------------------------
// Kernel 2/4: fused GATv2 attention. Block = (12-row i-tile, head), 384 thr.
// grid (32, 8) = 256 blocks = exactly 1 per CU (no second block-wave tail).
// Thread t == source node j. leaky(z) = 0.6 z + 0.4 |z|.
// Phase 1 pure-register VALU (gl_j, avec in VGPRs; gr via uniform s_loads),
// scores straight to LDS. Phase 2 softmax -> P bf16. Phase 3 MFMA P @ grT.
// LAYER 0: ELU + x residual -> xcur fp32. LAYER 1: + xcur -> out fp32.
// ---------------------------------------------------------------------------
template <int LAYER>
__global__ __launch_bounds__(384) void attn_fused(
    const float* __restrict__ G, const ushort_t* __restrict__ glb,
    const ushort_t* __restrict__ grT, const u64* __restrict__ mbits,
    const float* __restrict__ resid_in, const float* __restrict__ avec,
    float* __restrict__ xcur_out, float* __restrict__ f_out)
{
  // s_gl [384][72] bf16 = 55296 B, barrier-aliased with
  // { s_e fp32 12x384 (18432) + s_pb bf16 16x392 (12544) = 30976 }.
  __shared__ __align__(16) char smem[55296];
  ushort_t (*s_gl)[72]     = (ushort_t(*)[72])smem;
  float    (*s_e)[N_NODES] = (float(*)[N_NODES])smem;
  ushort_t (*s_pb)[392]    = (ushort_t(*)[392])(smem + 18432);
  __shared__ float s_bri[IT];
  __shared__ u64   s_mask[IT][6];

  const int t = threadIdx.x;
  const int i0 = blockIdx.x * IT, h = blockIdx.y;
  const int lane = t & 63, wave = t >> 6;

  // -- phase 0a: masks (72 u64) + bri dot (threads 128..320) --
  if (t < 72) ((u64*)s_mask)[t] = mbits[i0 * 6 + t];
  if (t >= 128 && t < 320) {
    int u = t - 128, il = u >> 4, fg = u & 15;
    float4 g4 = *(const float4*)(G + (i0 + il) * 1024 + 512 + h * 64 + fg * 4);
    float4 a4 = *(const float4*)(avec + fg * 4);
    float s = a4.x * g4.x + a4.y * g4.y + a4.z * g4.z + a4.w * g4.w;
    s += __shfl_xor(s, 1); s += __shfl_xor(s, 2);
    s += __shfl_xor(s, 4); s += __shfl_xor(s, 8);
    if (fg == 0) s_bri[il] = s;
  }
  // -- phase 0b: stage all 384 gl rows (bf16) coalesced into LDS --
#pragma unroll
  for (int rep = 0; rep < 8; ++rep) {
    int idx = rep * 384 + t, row = idx >> 3, c = idx & 7;
    *(short8*)&s_gl[row][c * 8] =
        *(const short8*)&glb[row * HF + h * 64 + c * 8];
  }
  __syncthreads();

  // -- own j-row -> 64 VGPRs; avec -> 64 VGPRs --
  float gl[64], av[64];
  {
    const short8* rowp = (const short8*)&s_gl[t][0];
#pragma unroll
    for (int c = 0; c < 8; ++c) {
      short8 v = rowp[c];
#pragma unroll
      for (int u2 = 0; u2 < 8; ++u2)
        gl[c * 8 + u2] = bf2f_u((ushort_t)v[u2]);
    }
#pragma unroll
    for (int c = 0; c < 16; ++c) {
      float4 a4 = ((const float4*)avec)[c];
      av[c * 4] = a4.x; av[c * 4 + 1] = a4.y;
      av[c * 4 + 2] = a4.z; av[c * 4 + 3] = a4.w;
    }
  }
  float accl = 0.f;
#pragma unroll
  for (int f = 0; f < 64; ++f) accl += av[f] * gl[f];
  __syncthreads();   // s_gl dead; region becomes s_e / s_pb

  // -- phase 1: scores, written straight to LDS (no private arrays) --
  const int jw = t >> 6, jb = t & 63;
#pragma unroll
  for (int il = 0; il < IT; ++il) {
    const float4* gr4 = (const float4*)(G + (i0 + il) * 1024 + 512 + h * 64);
    float acc = 0.f;
#pragma unroll
    for (int c = 0; c < 16; ++c) {
      float4 g4 = gr4[c];
      acc += av[c * 4]     * fabsf(gl[c * 4]     + g4.x);
      acc += av[c * 4 + 1] * fabsf(gl[c * 4 + 1] + g4.y);
      acc += av[c * 4 + 2] * fabsf(gl[c * 4 + 2] + g4.z);
      acc += av[c * 4 + 3] * fabsf(gl[c * 4 + 3] + g4.w);
    }
    bool m = (s_mask[il][jw] >> jb) & 1;
    float e = 0.6f * (accl + s_bri[il]) + 0.4f * acc;
    s_e[il][t] = m ? e : -1e30f;
  }
#pragma unroll
  for (int r4 = 0; r4 < 4; ++r4) s_pb[IT + r4][t] = 0;  // zero P rows 12..15
  __syncthreads();

  // -- phase 2: softmax over j per row; write normalized P bf16 --
  for (int il = wave; il < IT; il += 6) {
    float v[6];
    float mx = -1e30f;
#pragma unroll
    for (int c = 0; c < 6; ++c) { v[c] = s_e[il][lane + 64 * c]; mx = fmaxf(mx, v[c]); }
#pragma unroll
    for (int off = 32; off; off >>= 1) mx = fmaxf(mx, __shfl_xor(mx, off));
    float sum = 0.f;
#pragma unroll
    for (int c = 0; c < 6; ++c) { v[c] = __expf(v[c] - mx); sum += v[c]; }
#pragma unroll
    for (int off = 32; off; off >>= 1) sum += __shfl_xor(sum, off);
    float inv = 1.0f / sum;
#pragma unroll
    for (int c = 0; c < 6; ++c) s_pb[il][lane + 64 * c] = f2bf(v[c] * inv);
  }
  __syncthreads();

  // -- phase 3: MFMA aggregation out[12 i][64 f] = P[12][384] @ gr[384][64] --
  if (wave < 4) {
    const int lm = lane & 15, q = lane >> 4;
    const int f0 = wave * 16;
    const ushort_t* Brow = grT + (h * 64 + f0 + lm) * 384;
    f32x4 acc = {0.f, 0.f, 0.f, 0.f};
#pragma unroll
    for (int kc = 0; kc < 12; ++kc) {
      short8 af = *(const short8*)&s_pb[lm][kc * 32 + q * 8];
      short8 bf = *(const short8*)&Brow[kc * 32 + q * 8];
      acc = __builtin_amdgcn_mfma_f32_16x16x32_bf16(af, bf, acc, 0, 0, 0);
    }
    if (q < 3) {                                    // D rows 0..11
#pragma unroll
      for (int r = 0; r < 4; ++r) {
        int i = i0 + q * 4 + r;
        int off = i * HF + h * 64 + f0 + lm;
        float o = acc[r];
        if (LAYER == 0) {
          float oe = (o > 0.f) ? o : (__expf(o) - 1.f);   // ELU
          xcur_out[off] = resid_in[off] + oe;   // fp32 residual for layer 1
        } else {
          f_out[off] = resid_in[off] + o;       // final output, fp32
        }
      }
    }
  }
}

// ---------------------------------------------------------------------------
extern "C" void kernel_launch(void* const* d_in, const int* in_sizes, int n_in,
                              void* d_out, int out_size, void* d_ws, size_t ws_size,
                              hipStream_t stream) {
  const float* x   = (const float*)d_in[0];
  const int*   adj = (const int*)d_in[1];
  const float* Wl0 = (const float*)d_in[2];
  const float* Wr0 = (const float*)d_in[3];
  const float* a0  = (const float*)d_in[4];
  const float* Wl1 = (const float*)d_in[5];
  const float* Wr1 = (const float*)d_in[6];
  const float* a1  = (const float*)d_in[7];
  float* out = (float*)d_out;

  char* ws = (char*)d_ws;
  float*    G    = (float*)   (ws + 0L);            // 1.5 MB (gr half used)
  ushort_t* grT  = (ushort_t*)(ws + (2L << 20));    // 384 KB gr^T bf16
  ushort_t* glb  = (ushort_t*)(ws + (3L << 20));    // 384 KB gl bf16
  u64*      mbits= (u64*)     (ws + (4L << 20));    // 18 KB adjacency bits
  float*    xcur = (float*)   (ws + (5L << 20));    // 768 KB fp32 residual

  gemm_direct<<<dim3(24, 8), 256, 0, stream>>>(x, Wl0, Wr0, G, glb, grT,
                                               adj, mbits);
  attn_fused<0><<<dim3(32, 8), 384, 0, stream>>>(G, glb, grT, mbits, x, a0,
                                                 xcur, nullptr);
  gemm_direct<<<dim3(24, 8), 256, 0, stream>>>(xcur, Wl1, Wr1, G, glb, grT,
                                               nullptr, nullptr);
  attn_fused<1><<<dim3(32, 8), 384, 0, stream>>>(G, glb, grT, mbits, xcur, a1,
                                                 nullptr, out);
}